// Round 1
// baseline (4338.845 us; speedup 1.0000x reference)
//
#include <hip/hip_runtime.h>

#define DH 128      // feature dim
#define TE 128      // rows (edges or nodes) per tile
#define KC 32       // k-chunk
#define NTH 256

// ---- sortable-uint encoding for float atomic max ----
__device__ __forceinline__ unsigned enc_f(float f) {
    unsigned u = __float_as_uint(f);
    return (u & 0x80000000u) ? ~u : (u | 0x80000000u);
}
__device__ __forceinline__ float dec_f(unsigned u) {
    unsigned b = (u & 0x80000000u) ? (u ^ 0x80000000u) : ~u;
    return __uint_as_float(b);
}
#define ENC_NEG_INF 0x007FFFFFu   // enc(-inf)

__global__ void fill_kernel(unsigned* __restrict__ p, int n) {
    int i = blockIdx.x * blockDim.x + threadIdx.x;
    int stride = gridDim.x * blockDim.x;
    for (; i < n; i += stride) p[i] = ENC_NEG_INF;
}

__global__ void finalize_kernel(const unsigned* __restrict__ agg,
                                float* __restrict__ out, int n, int dorelu) {
    int i = blockIdx.x * blockDim.x + threadIdx.x;
    int stride = gridDim.x * blockDim.x;
    for (; i < n; i += stride) {
        unsigned uv = agg[i];
        float f = (uv == ENC_NEG_INF) ? 0.0f : dec_f(uv);
        if (dorelu) f = fmaxf(f, 0.0f);
        out[i] = f;
    }
}

// C[n][c] = sum_k h[n][k] * W[k][c]   (h: [N][128], W: [128][128])
__global__ __launch_bounds__(NTH) void gemm_node(
    const float* __restrict__ h, const float* __restrict__ W,
    float* __restrict__ out, int N) {
    __shared__ float Xt[KC][TE + 4];
    __shared__ float Wc[KC][DH];
    const int n0 = blockIdx.x * TE;
    const int t = threadIdx.x;
    const int u = t & 15, v = t >> 4;
    const int r = t >> 1, half = t & 1;
    int n = n0 + r; if (n >= N) n = N - 1;
    const float* hp = &h[(size_t)n * DH + half * 16];
    float acc[2][2][4][4] = {};
    for (int kc = 0; kc < DH; kc += KC) {
        __syncthreads();
        #pragma unroll
        for (int i = t; i < KC * DH / 4; i += NTH) {
            int kr = i >> 5, cc = (i & 31) << 2;
            *(float4*)&Wc[kr][cc] = *(const float4*)&W[(size_t)(kc + kr) * DH + cc];
        }
        #pragma unroll
        for (int q = 0; q < 4; ++q) {
            float4 x = *(const float4*)&hp[kc + q * 4];
            int kl = half * 16 + q * 4;
            Xt[kl + 0][r] = x.x; Xt[kl + 1][r] = x.y;
            Xt[kl + 2][r] = x.z; Xt[kl + 3][r] = x.w;
        }
        __syncthreads();
        #pragma unroll
        for (int k = 0; k < KC; ++k) {
            float a[2][4], b[2][4];
            float4 t0 = *(const float4*)&Xt[k][4 * u];
            float4 t1 = *(const float4*)&Xt[k][64 + 4 * u];
            float4 w0 = *(const float4*)&Wc[k][4 * v];
            float4 w1 = *(const float4*)&Wc[k][64 + 4 * v];
            a[0][0]=t0.x; a[0][1]=t0.y; a[0][2]=t0.z; a[0][3]=t0.w;
            a[1][0]=t1.x; a[1][1]=t1.y; a[1][2]=t1.z; a[1][3]=t1.w;
            b[0][0]=w0.x; b[0][1]=w0.y; b[0][2]=w0.z; b[0][3]=w0.w;
            b[1][0]=w1.x; b[1][1]=w1.y; b[1][2]=w1.z; b[1][3]=w1.w;
            #pragma unroll
            for (int ri = 0; ri < 2; ++ri)
                #pragma unroll
                for (int i = 0; i < 4; ++i)
                    #pragma unroll
                    for (int ci = 0; ci < 2; ++ci)
                        #pragma unroll
                        for (int j = 0; j < 4; ++j)
                            acc[ri][ci][i][j] = fmaf(a[ri][i], b[ci][j], acc[ri][ci][i][j]);
        }
    }
    #pragma unroll
    for (int ri = 0; ri < 2; ++ri)
        #pragma unroll
        for (int i = 0; i < 4; ++i) {
            int row = ri * 64 + 4 * u + i;
            int nn = n0 + row;
            if (nn >= N) continue;
            #pragma unroll
            for (int ci = 0; ci < 2; ++ci)
                #pragma unroll
                for (int j = 0; j < 4; ++j)
                    out[(size_t)nn * DH + ci * 64 + 4 * v + j] = acc[ri][ci][i][j];
        }
}

// per-edge: v = relu(A[dst] + B[src] + b1); m = v @ W2 + b2; atomic segmax into agg[dst]
__global__ __launch_bounds__(NTH) void edge_mlp(
    const float* __restrict__ A, const float* __restrict__ B,
    const int* __restrict__ src, const int* __restrict__ dst,
    const float* __restrict__ b1, const float* __restrict__ W2,
    const float* __restrict__ b2, unsigned* __restrict__ agg, int E) {
    __shared__ float Vt[KC][TE + 4];
    __shared__ float Wc[KC][DH];
    __shared__ int sdst[TE], ssrc[TE];
    __shared__ float sb2[DH];
    const int e0 = blockIdx.x * TE;
    const int t = threadIdx.x;
    if (t < TE) { sdst[t] = dst[e0 + t]; ssrc[t] = src[e0 + t]; }
    if (t < DH) sb2[t] = b2[t];
    const int u = t & 15, v = t >> 4;
    const int r = t >> 1, half = t & 1;
    float acc[2][2][4][4] = {};
    __syncthreads();
    const int dn = sdst[r], sn = ssrc[r];
    const float* Ap = &A[(size_t)dn * DH + half * 16];
    const float* Bp = &B[(size_t)sn * DH + half * 16];
    const float* b1p = &b1[half * 16];
    for (int kc = 0; kc < DH; kc += KC) {
        __syncthreads();
        #pragma unroll
        for (int i = t; i < KC * DH / 4; i += NTH) {
            int kr = i >> 5, cc = (i & 31) << 2;
            *(float4*)&Wc[kr][cc] = *(const float4*)&W2[(size_t)(kc + kr) * DH + cc];
        }
        #pragma unroll
        for (int q = 0; q < 4; ++q) {
            float4 xa = *(const float4*)&Ap[kc + q * 4];
            float4 xb = *(const float4*)&Bp[kc + q * 4];
            float4 xc = *(const float4*)&b1p[kc + q * 4];
            int kl = half * 16 + q * 4;
            Vt[kl + 0][r] = fmaxf(xa.x + xb.x + xc.x, 0.0f);
            Vt[kl + 1][r] = fmaxf(xa.y + xb.y + xc.y, 0.0f);
            Vt[kl + 2][r] = fmaxf(xa.z + xb.z + xc.z, 0.0f);
            Vt[kl + 3][r] = fmaxf(xa.w + xb.w + xc.w, 0.0f);
        }
        __syncthreads();
        #pragma unroll
        for (int k = 0; k < KC; ++k) {
            float a[2][4], b[2][4];
            float4 t0 = *(const float4*)&Vt[k][4 * u];
            float4 t1 = *(const float4*)&Vt[k][64 + 4 * u];
            float4 w0 = *(const float4*)&Wc[k][4 * v];
            float4 w1 = *(const float4*)&Wc[k][64 + 4 * v];
            a[0][0]=t0.x; a[0][1]=t0.y; a[0][2]=t0.z; a[0][3]=t0.w;
            a[1][0]=t1.x; a[1][1]=t1.y; a[1][2]=t1.z; a[1][3]=t1.w;
            b[0][0]=w0.x; b[0][1]=w0.y; b[0][2]=w0.z; b[0][3]=w0.w;
            b[1][0]=w1.x; b[1][1]=w1.y; b[1][2]=w1.z; b[1][3]=w1.w;
            #pragma unroll
            for (int ri = 0; ri < 2; ++ri)
                #pragma unroll
                for (int i = 0; i < 4; ++i)
                    #pragma unroll
                    for (int ci = 0; ci < 2; ++ci)
                        #pragma unroll
                        for (int j = 0; j < 4; ++j)
                            acc[ri][ci][i][j] = fmaf(a[ri][i], b[ci][j], acc[ri][ci][i][j]);
        }
    }
    #pragma unroll
    for (int ri = 0; ri < 2; ++ri)
        #pragma unroll
        for (int i = 0; i < 4; ++i) {
            int row = ri * 64 + 4 * u + i;
            int d = sdst[row];
            unsigned* ap = &agg[(size_t)d * DH];
            #pragma unroll
            for (int ci = 0; ci < 2; ++ci)
                #pragma unroll
                for (int j = 0; j < 4; ++j) {
                    int col = ci * 64 + 4 * v + j;
                    float m = acc[ri][ci][i][j] + sb2[col];
                    atomicMax(&ap[col], enc_f(m));
                }
        }
}

extern "C" void kernel_launch(void* const* d_in, const int* in_sizes, int n_in,
                              void* d_out, int out_size, void* d_ws, size_t ws_size,
                              hipStream_t stream) {
    const float* z  = (const float*)d_in[0];
    const int*   ei = (const int*)d_in[1];
    const float* W1 = (const float*)d_in[2];
    const float* b1 = (const float*)d_in[3];
    const float* W2 = (const float*)d_in[4];
    const float* b2 = (const float*)d_in[5];
    const int N = 50000, D = DH, E = 800000, L = 3;
    const int* srcp = ei;
    const int* dstp = ei + E;

    float* hbuf = (float*)d_ws;
    float* Abuf = hbuf + (size_t)N * D;
    float* Bbuf = Abuf + (size_t)N * D;
    unsigned* agg = (unsigned*)(Bbuf + (size_t)N * D);
    float* outp = (float*)d_out;

    const int nblk_n = (N + TE - 1) / TE;
    for (int l = 0; l < L; ++l) {
        const float* h = (l == 0) ? z : hbuf;
        const float* W1l = W1 + (size_t)l * 2 * D * D;
        gemm_node<<<nblk_n, NTH, 0, stream>>>(h, W1l,         Abuf, N);
        gemm_node<<<nblk_n, NTH, 0, stream>>>(h, W1l + D * D, Bbuf, N);
        fill_kernel<<<2048, 256, 0, stream>>>(agg, N * D);
        edge_mlp<<<E / TE, NTH, 0, stream>>>(Abuf, Bbuf, srcp, dstp,
                                             b1 + (size_t)l * D,
                                             W2 + (size_t)l * D * D,
                                             b2 + (size_t)l * D, agg, E);
        finalize_kernel<<<2048, 256, 0, stream>>>(agg, (l == L - 1) ? outp : hbuf,
                                                  N * D, (l < L - 1) ? 1 : 0);
    }
}

// Round 2
// 1529.328 us; speedup vs baseline: 2.8371x; 2.8371x over previous
//
#include <hip/hip_runtime.h>

#define DH 128      // feature dim
#define TE 128      // rows (edges or nodes) per tile
#define KC 32       // k-chunk
#define NTH 256

// ---- sortable-uint encoding for float atomic max ----
__device__ __forceinline__ unsigned enc_f(float f) {
    unsigned u = __float_as_uint(f);
    return (u & 0x80000000u) ? ~u : (u | 0x80000000u);
}
__device__ __forceinline__ float dec_f(unsigned u) {
    unsigned b = (u & 0x80000000u) ? (u ^ 0x80000000u) : ~u;
    return __uint_as_float(b);
}
#define ENC_NEG_INF 0x007FFFFFu   // enc(-inf)

__global__ void fill_u(unsigned* __restrict__ p, int n, unsigned v) {
    int i = blockIdx.x * blockDim.x + threadIdx.x;
    int stride = gridDim.x * blockDim.x;
    for (; i < n; i += stride) p[i] = v;
}

__global__ void hist_kernel(const int* __restrict__ dst, unsigned* __restrict__ cnt, int E) {
    int e = blockIdx.x * blockDim.x + threadIdx.x;
    int stride = gridDim.x * blockDim.x;
    for (; e < E; e += stride) atomicAdd(&cnt[dst[e]], 1u);
}

// single-block exclusive scan of cnt[0..n) -> off; zeroes cnt for reuse as cursor
__global__ __launch_bounds__(1024) void scan_kernel(unsigned* __restrict__ cnt,
                                                    unsigned* __restrict__ off, int n) {
    __shared__ unsigned s[1024];
    __shared__ unsigned base;
    const int t = threadIdx.x;
    if (t == 0) base = 0;
    __syncthreads();
    for (int c0 = 0; c0 < n; c0 += 1024) {
        int idx = c0 + t;
        unsigned v = (idx < n) ? cnt[idx] : 0u;
        if (idx < n) cnt[idx] = 0u;
        s[t] = v;
        __syncthreads();
        for (int d = 1; d < 1024; d <<= 1) {
            unsigned u = (t >= d) ? s[t - d] : 0u;
            __syncthreads();
            s[t] += u;
            __syncthreads();
        }
        if (idx < n) off[idx] = base + s[t] - v;
        __syncthreads();
        if (t == 0) base += s[1023];
        __syncthreads();
    }
}

__global__ void scatter_kernel(const int* __restrict__ src, const int* __restrict__ dst,
                               const unsigned* __restrict__ off, unsigned* __restrict__ cur,
                               int* __restrict__ s_src, int* __restrict__ s_dst, int E) {
    int e = blockIdx.x * blockDim.x + threadIdx.x;
    int stride = gridDim.x * blockDim.x;
    for (; e < E; e += stride) {
        int d = dst[e];
        unsigned p = off[d] + atomicAdd(&cur[d], 1u);
        s_src[p] = src[e];
        s_dst[p] = d;
    }
}

// C[n][c] = sum_k h[n][k] * W[k][c] (+ bias[c])   (h: [N][128], W: [128][128])
__global__ __launch_bounds__(NTH) void gemm_node(
    const float* __restrict__ h, const float* __restrict__ W,
    const float* __restrict__ bias, float* __restrict__ out, int N) {
    __shared__ float Xt[KC][TE + 4];
    __shared__ float Wc[KC][DH];
    const int n0 = blockIdx.x * TE;
    const int t = threadIdx.x;
    const int u = t & 15, v = t >> 4;
    const int r = t >> 1, half = t & 1;
    int n = n0 + r; if (n >= N) n = N - 1;
    const float* hp = &h[(size_t)n * DH + half * 16];
    float acc[2][2][4][4] = {};
    for (int kc = 0; kc < DH; kc += KC) {
        __syncthreads();
        #pragma unroll
        for (int i = t; i < KC * DH / 4; i += NTH) {
            int kr = i >> 5, cc = (i & 31) << 2;
            *(float4*)&Wc[kr][cc] = *(const float4*)&W[(size_t)(kc + kr) * DH + cc];
        }
        #pragma unroll
        for (int q = 0; q < 4; ++q) {
            float4 x = *(const float4*)&hp[kc + q * 4];
            int kl = half * 16 + q * 4;
            Xt[kl + 0][r] = x.x; Xt[kl + 1][r] = x.y;
            Xt[kl + 2][r] = x.z; Xt[kl + 3][r] = x.w;
        }
        __syncthreads();
        #pragma unroll
        for (int k = 0; k < KC; ++k) {
            float a[2][4], b[2][4];
            float4 t0 = *(const float4*)&Xt[k][4 * u];
            float4 t1 = *(const float4*)&Xt[k][64 + 4 * u];
            float4 w0 = *(const float4*)&Wc[k][4 * v];
            float4 w1 = *(const float4*)&Wc[k][64 + 4 * v];
            a[0][0]=t0.x; a[0][1]=t0.y; a[0][2]=t0.z; a[0][3]=t0.w;
            a[1][0]=t1.x; a[1][1]=t1.y; a[1][2]=t1.z; a[1][3]=t1.w;
            b[0][0]=w0.x; b[0][1]=w0.y; b[0][2]=w0.z; b[0][3]=w0.w;
            b[1][0]=w1.x; b[1][1]=w1.y; b[1][2]=w1.z; b[1][3]=w1.w;
            #pragma unroll
            for (int ri = 0; ri < 2; ++ri)
                #pragma unroll
                for (int i = 0; i < 4; ++i)
                    #pragma unroll
                    for (int ci = 0; ci < 2; ++ci)
                        #pragma unroll
                        for (int j = 0; j < 4; ++j)
                            acc[ri][ci][i][j] = fmaf(a[ri][i], b[ci][j], acc[ri][ci][i][j]);
        }
    }
    #pragma unroll
    for (int ri = 0; ri < 2; ++ri)
        #pragma unroll
        for (int i = 0; i < 4; ++i) {
            int row = ri * 64 + 4 * u + i;
            int nn = n0 + row;
            if (nn >= N) continue;
            #pragma unroll
            for (int ci = 0; ci < 2; ++ci)
                #pragma unroll
                for (int j = 0; j < 4; ++j) {
                    int col = ci * 64 + 4 * v + j;
                    float bv = bias ? bias[col] : 0.0f;
                    out[(size_t)nn * DH + col] = acc[ri][ci][i][j] + bv;
                }
        }
}

// per sorted-edge tile: v = relu(A[dst] + B[src]); m = v @ W2;
// segmented max over sorted dst runs in LDS, then few atomics into agg.
__global__ __launch_bounds__(NTH) void edge_mlp(
    const float* __restrict__ A, const float* __restrict__ B,
    const int* __restrict__ src, const int* __restrict__ dst,
    const float* __restrict__ W2, unsigned* __restrict__ agg, int E) {
    __shared__ __align__(16) char smem[33280];
    float (*Vt)[TE + 4] = (float (*)[TE + 4])smem;                    // 32 x 132
    float (*Wc)[DH]     = (float (*)[DH])(smem + 32 * (TE + 4) * 4);  // 32 x 128
    float (*R)[64]      = (float (*)[64])smem;                        // 128 x 64 (reuse)
    __shared__ int sdst[TE], ssrc[TE];
    const int e0 = blockIdx.x * TE;
    const int t = threadIdx.x;
    if (t < TE) { sdst[t] = dst[e0 + t]; ssrc[t] = src[e0 + t]; }
    const int u = t & 15, v = t >> 4;
    const int r = t >> 1, half16 = t & 1;
    float acc[2][2][4][4] = {};
    __syncthreads();
    const int dn = sdst[r], sn = ssrc[r];
    const float* Ap = &A[(size_t)dn * DH + half16 * 16];
    const float* Bp = &B[(size_t)sn * DH + half16 * 16];
    for (int kc = 0; kc < DH; kc += KC) {
        __syncthreads();
        #pragma unroll
        for (int i = t; i < KC * DH / 4; i += NTH) {
            int kr = i >> 5, cc = (i & 31) << 2;
            *(float4*)&Wc[kr][cc] = *(const float4*)&W2[(size_t)(kc + kr) * DH + cc];
        }
        #pragma unroll
        for (int q = 0; q < 4; ++q) {
            float4 xa = *(const float4*)&Ap[kc + q * 4];
            float4 xb = *(const float4*)&Bp[kc + q * 4];
            int kl = half16 * 16 + q * 4;
            Vt[kl + 0][r] = fmaxf(xa.x + xb.x, 0.0f);
            Vt[kl + 1][r] = fmaxf(xa.y + xb.y, 0.0f);
            Vt[kl + 2][r] = fmaxf(xa.z + xb.z, 0.0f);
            Vt[kl + 3][r] = fmaxf(xa.w + xb.w, 0.0f);
        }
        __syncthreads();
        #pragma unroll
        for (int k = 0; k < KC; ++k) {
            float a[2][4], b[2][4];
            float4 t0 = *(const float4*)&Vt[k][4 * u];
            float4 t1 = *(const float4*)&Vt[k][64 + 4 * u];
            float4 w0 = *(const float4*)&Wc[k][4 * v];
            float4 w1 = *(const float4*)&Wc[k][64 + 4 * v];
            a[0][0]=t0.x; a[0][1]=t0.y; a[0][2]=t0.z; a[0][3]=t0.w;
            a[1][0]=t1.x; a[1][1]=t1.y; a[1][2]=t1.z; a[1][3]=t1.w;
            b[0][0]=w0.x; b[0][1]=w0.y; b[0][2]=w0.z; b[0][3]=w0.w;
            b[1][0]=w1.x; b[1][1]=w1.y; b[1][2]=w1.z; b[1][3]=w1.w;
            #pragma unroll
            for (int ri = 0; ri < 2; ++ri)
                #pragma unroll
                for (int i = 0; i < 4; ++i)
                    #pragma unroll
                    for (int ci = 0; ci < 2; ++ci)
                        #pragma unroll
                        for (int j = 0; j < 4; ++j)
                            acc[ri][ci][i][j] = fmaf(a[ri][i], b[ci][j], acc[ri][ci][i][j]);
        }
    }
    // segmented max: stage tile half (128 rows x 64 cols) in LDS, reduce sorted runs
    #pragma unroll
    for (int half = 0; half < 2; ++half) {
        __syncthreads();   // half0: protect Vt/Wc readers; half1: protect prior reduce readers
        #pragma unroll
        for (int ri = 0; ri < 2; ++ri)
            #pragma unroll
            for (int i = 0; i < 4; ++i) {
                int row = ri * 64 + 4 * u + i;
                int cs = (4 * v) ^ ((row & 15) << 2);   // XOR swizzle, keeps b128 at floor
                float4 val;
                val.x = acc[ri][half][i][0]; val.y = acc[ri][half][i][1];
                val.z = acc[ri][half][i][2]; val.w = acc[ri][half][i][3];
                *(float4*)&R[row][cs] = val;
            }
        __syncthreads();
        const int col = t & 63;
        const int r0 = (t >> 6) * 32;
        float run = R[r0][col ^ ((r0 & 15) << 2)];
        int cur = sdst[r0];
        for (int rr = r0 + 1; rr < r0 + 32; ++rr) {
            float x = R[rr][col ^ ((rr & 15) << 2)];
            int d = sdst[rr];
            if (d != cur) {
                atomicMax(&agg[(size_t)cur * DH + half * 64 + col], enc_f(run));
                cur = d; run = x;
            } else {
                run = fmaxf(run, x);
            }
        }
        atomicMax(&agg[(size_t)cur * DH + half * 64 + col], enc_f(run));
    }
}

// out = (agg empty ? 0 : dec(agg) + b2[col]); optional relu. May alias agg (elementwise).
__global__ void finalize_kernel(unsigned* __restrict__ agg, float* __restrict__ out,
                                const float* __restrict__ b2, int n, int dorelu) {
    int i = blockIdx.x * blockDim.x + threadIdx.x;
    int stride = gridDim.x * blockDim.x;
    for (; i < n; i += stride) {
        unsigned uv = agg[i];
        float f = (uv == ENC_NEG_INF) ? 0.0f : dec_f(uv) + b2[i & (DH - 1)];
        if (dorelu) f = fmaxf(f, 0.0f);
        out[i] = f;
    }
}

extern "C" void kernel_launch(void* const* d_in, const int* in_sizes, int n_in,
                              void* d_out, int out_size, void* d_ws, size_t ws_size,
                              hipStream_t stream) {
    const float* z  = (const float*)d_in[0];
    const int*   ei = (const int*)d_in[1];
    const float* W1 = (const float*)d_in[2];
    const float* b1 = (const float*)d_in[3];
    const float* W2 = (const float*)d_in[4];
    const float* b2 = (const float*)d_in[5];
    const int N = 50000, D = DH, E = 800000, L = 3;
    const int* srcp = ei;
    const int* dstp = ei + E;

    // ws layout (h aliases agg between layers): A, B, agg, cnt, off, sorted src/dst
    float* Abuf = (float*)d_ws;
    float* Bbuf = Abuf + (size_t)N * D;
    unsigned* agg = (unsigned*)(Bbuf + (size_t)N * D);
    unsigned* cnt = agg + (size_t)N * D;
    unsigned* off = cnt + N;
    int* s_src = (int*)(off + N + 4);
    int* s_dst = s_src + E;
    float* outp = (float*)d_out;

    // ---- counting sort of edges by dst (once; reused by all layers) ----
    fill_u<<<256, 256, 0, stream>>>(cnt, N, 0u);
    hist_kernel<<<1024, 256, 0, stream>>>(dstp, cnt, E);
    scan_kernel<<<1, 1024, 0, stream>>>(cnt, off, N);
    scatter_kernel<<<1024, 256, 0, stream>>>(srcp, dstp, off, cnt, s_src, s_dst, E);

    const int nblk_n = (N + TE - 1) / TE;
    for (int l = 0; l < L; ++l) {
        const float* h = (l == 0) ? z : (const float*)agg;
        const float* W1l = W1 + (size_t)l * 2 * D * D;
        gemm_node<<<nblk_n, NTH, 0, stream>>>(h, W1l,         b1 + (size_t)l * D, Abuf, N);
        gemm_node<<<nblk_n, NTH, 0, stream>>>(h, W1l + D * D, nullptr,            Bbuf, N);
        fill_u<<<2048, 256, 0, stream>>>(agg, N * D, ENC_NEG_INF);
        edge_mlp<<<E / TE, NTH, 0, stream>>>(Abuf, Bbuf, s_src, s_dst,
                                             W2 + (size_t)l * D * D, agg, E);
        finalize_kernel<<<2048, 256, 0, stream>>>(agg, (l == L - 1) ? outp : (float*)agg,
                                                  b2 + (size_t)l * D, N * D,
                                                  (l < L - 1) ? 1 : 0);
    }
}

// Round 4
// 1023.802 us; speedup vs baseline: 4.2380x; 1.4938x over previous
//
#include <hip/hip_runtime.h>

#define DH 128
#define NLAYER 3
typedef unsigned short ushort_t;
typedef __attribute__((ext_vector_type(8))) short bf16x8;
typedef __attribute__((ext_vector_type(4))) float f32x4;

// ---- bf16 split helpers (RNE) ----
__device__ __forceinline__ ushort_t f2bf(float a) {
    unsigned u = __float_as_uint(a);
    return (ushort_t)((u + 0x7fffu + ((u >> 16) & 1u)) >> 16);
}
__device__ __forceinline__ float bf2f(ushort_t h) {
    return __uint_as_float(((unsigned)h) << 16);
}

// ---- sortable-uint encoding for float atomic max ----
__device__ __forceinline__ unsigned enc_f(float f) {
    unsigned u = __float_as_uint(f);
    return (u & 0x80000000u) ? ~u : (u | 0x80000000u);
}
__device__ __forceinline__ float dec_f(unsigned u) {
    unsigned b = (u & 0x80000000u) ? (u ^ 0x80000000u) : ~u;
    return __uint_as_float(b);
}
#define ENC_NEG_INF 0x007FFFFFu

__global__ void fill_u(unsigned* __restrict__ p, int n, unsigned v) {
    int i = blockIdx.x * blockDim.x + threadIdx.x;
    int stride = gridDim.x * blockDim.x;
    for (; i < n; i += stride) p[i] = v;
}

__global__ void hist_kernel(const int* __restrict__ dst, unsigned* __restrict__ cnt, int E) {
    int e = blockIdx.x * blockDim.x + threadIdx.x;
    int stride = gridDim.x * blockDim.x;
    for (; e < E; e += stride) atomicAdd(&cnt[dst[e]], 1u);
}

__global__ __launch_bounds__(1024) void scan_kernel(unsigned* __restrict__ cnt,
                                                    unsigned* __restrict__ off, int n) {
    __shared__ unsigned s[1024];
    __shared__ unsigned base;
    const int t = threadIdx.x;
    if (t == 0) base = 0;
    __syncthreads();
    for (int c0 = 0; c0 < n; c0 += 1024) {
        int idx = c0 + t;
        unsigned v = (idx < n) ? cnt[idx] : 0u;
        if (idx < n) cnt[idx] = 0u;
        s[t] = v;
        __syncthreads();
        for (int d = 1; d < 1024; d <<= 1) {
            unsigned u = (t >= d) ? s[t - d] : 0u;
            __syncthreads();
            s[t] += u;
            __syncthreads();
        }
        if (idx < n) off[idx] = base + s[t] - v;
        __syncthreads();
        if (t == 0) base += s[1023];
        __syncthreads();
    }
}

__global__ void scatter_kernel(const int* __restrict__ src, const int* __restrict__ dst,
                               const unsigned* __restrict__ off, unsigned* __restrict__ cur,
                               int* __restrict__ s_src, int* __restrict__ s_dst, int E) {
    int e = blockIdx.x * blockDim.x + threadIdx.x;
    int stride = gridDim.x * blockDim.x;
    for (; e < E; e += stride) {
        int d = dst[e];
        unsigned p = off[d] + atomicAdd(&cur[d], 1u);
        s_src[p] = src[e];
        s_dst[p] = d;
    }
}

// W1t[l][c'][k]: c'<128 -> A-cols (W1[l][k][c']), c'>=128 -> B-cols (W1[l][128+k][c'-128])
// W2t[l][c][k] = W2[l][k][c]. All split into hi/lo bf16.
__global__ void convert_w(const float* __restrict__ W1, const float* __restrict__ W2,
                          ushort_t* __restrict__ W1t_hi, ushort_t* __restrict__ W1t_lo,
                          ushort_t* __restrict__ W2t_hi, ushort_t* __restrict__ W2t_lo) {
    const int T1 = NLAYER * 256 * DH, T2 = NLAYER * DH * DH;
    int i = blockIdx.x * blockDim.x + threadIdx.x;
    int stride = gridDim.x * blockDim.x;
    for (; i < T1 + T2; i += stride) {
        if (i < T1) {
            int l = i >> 15, r = i & 32767, c = r >> 7, k = r & 127;
            float w = W1[(size_t)l * 32768 + (size_t)((c < 128) ? k : 128 + k) * DH + (c & 127)];
            ushort_t hi = f2bf(w);
            W1t_hi[i] = hi; W1t_lo[i] = f2bf(w - bf2f(hi));
        } else {
            int j = i - T1;
            int l = j >> 14, r = j & 16383, c = r >> 7, k = r & 127;
            float w = W2[(size_t)l * 16384 + (size_t)k * DH + c];
            ushort_t hi = f2bf(w);
            W2t_hi[j] = hi; W2t_lo[j] = f2bf(w - bf2f(hi));
        }
    }
}

// z -> packed (hi | lo<<16) per element, into hpk
__global__ void convert_h(const float* __restrict__ z, unsigned* __restrict__ hpk, int n) {
    int i = blockIdx.x * blockDim.x + threadIdx.x;
    int stride = gridDim.x * blockDim.x;
    for (; i < n; i += stride) {
        float a = z[i];
        ushort_t hi = f2bf(a);
        ushort_t lo = f2bf(a - bf2f(hi));
        hpk[i] = (unsigned)hi | ((unsigned)lo << 16);
    }
}

// C[row, col] = sum_k h[row][k] * Wt[col][k]  via split-bf16 MFMA.
// h packed u32 (hi|lo). Block: 128 rows x 128 cols, 4 waves (each 32 rows x 128 cols).
__global__ __launch_bounds__(256, 2) void node_gemm(
    const unsigned* __restrict__ hpk,
    const ushort_t* __restrict__ wthi, const ushort_t* __restrict__ wtlo,
    const float* __restrict__ bias, float* __restrict__ outp, int N) {
    __shared__ char smem[65536];
    char* Whi = smem;
    char* Wlo = smem + 32768;
    const int t = threadIdx.x;
    const int w = t >> 6, l = t & 63;
    // coop load W tile (hi/lo) with 16B-chunk XOR swizzle
    for (int cid = t; cid < 2048; cid += 256) {
        int c = cid >> 4, ch = cid & 15;
        uint4 vh = *(const uint4*)(wthi + (size_t)cid * 8);
        uint4 vl = *(const uint4*)(wtlo + (size_t)cid * 8);
        *(uint4*)(Whi + c * 256 + ((ch ^ (c & 15)) << 4)) = vh;
        *(uint4*)(Wlo + c * 256 + ((ch ^ (c & 15)) << 4)) = vl;
    }
    const int n0 = blockIdx.x * 128;
    bf16x8 ahi[2][4], alo[2][4];
    #pragma unroll
    for (int rt = 0; rt < 2; ++rt) {
        int row = n0 + w * 32 + rt * 16 + (l & 15);
        if (row >= N) row = N - 1;
        const unsigned* ph = hpk + (size_t)row * DH + 8 * (l >> 4);
        #pragma unroll
        for (int ks = 0; ks < 4; ++ks) {
            uint4 p0 = *(const uint4*)(ph + ks * 32);
            uint4 p1 = *(const uint4*)(ph + ks * 32 + 4);
            bf16x8 hv, lv;
            hv[0] = (short)(p0.x & 0xffffu); lv[0] = (short)(p0.x >> 16);
            hv[1] = (short)(p0.y & 0xffffu); lv[1] = (short)(p0.y >> 16);
            hv[2] = (short)(p0.z & 0xffffu); lv[2] = (short)(p0.z >> 16);
            hv[3] = (short)(p0.w & 0xffffu); lv[3] = (short)(p0.w >> 16);
            hv[4] = (short)(p1.x & 0xffffu); lv[4] = (short)(p1.x >> 16);
            hv[5] = (short)(p1.y & 0xffffu); lv[5] = (short)(p1.y >> 16);
            hv[6] = (short)(p1.z & 0xffffu); lv[6] = (short)(p1.z >> 16);
            hv[7] = (short)(p1.w & 0xffffu); lv[7] = (short)(p1.w >> 16);
            ahi[rt][ks] = hv; alo[rt][ks] = lv;
        }
    }
    f32x4 acc[2][8];
    #pragma unroll
    for (int rt = 0; rt < 2; ++rt)
        #pragma unroll
        for (int ct = 0; ct < 8; ++ct) acc[rt][ct] = (f32x4){0.f, 0.f, 0.f, 0.f};
    __syncthreads();
    #pragma unroll
    for (int ct = 0; ct < 8; ++ct) {
        int colv = ct * 16 + (l & 15);
        #pragma unroll
        for (int ks = 0; ks < 4; ++ks) {
            int chb = ks * 4 + (l >> 4);
            int addr = colv * 256 + ((chb ^ (colv & 15)) << 4);
            bf16x8 bh = *(const bf16x8*)(Whi + addr);
            bf16x8 bl = *(const bf16x8*)(Wlo + addr);
            #pragma unroll
            for (int rt = 0; rt < 2; ++rt) {
                acc[rt][ct] = __builtin_amdgcn_mfma_f32_16x16x32_bf16(ahi[rt][ks], bh, acc[rt][ct], 0, 0, 0);
                acc[rt][ct] = __builtin_amdgcn_mfma_f32_16x16x32_bf16(ahi[rt][ks], bl, acc[rt][ct], 0, 0, 0);
                acc[rt][ct] = __builtin_amdgcn_mfma_f32_16x16x32_bf16(alo[rt][ks], bh, acc[rt][ct], 0, 0, 0);
            }
        }
    }
    #pragma unroll
    for (int ct = 0; ct < 8; ++ct) {
        int col = ct * 16 + (l & 15);
        float bv = bias ? bias[col] : 0.0f;
        #pragma unroll
        for (int rt = 0; rt < 2; ++rt)
            #pragma unroll
            for (int i = 0; i < 4; ++i) {
                int row = n0 + w * 32 + rt * 16 + (l >> 4) * 4 + i;
                if (row < N) outp[(size_t)row * DH + col] = acc[rt][ct][i] + bv;
            }
    }
}

// Edge kernel: 256 sorted edges x 128 cols per block, 8 waves.
// V = relu(A[dst]+B[src]) gathered+split directly into A-fragments (registers).
// W2t hi/lo in LDS (swizzled). Segmented-max epilogue via LDS staging (overlays Whi).
__global__ __launch_bounds__(512, 2) void edge_mlp(
    const float* __restrict__ Afp, const float* __restrict__ Bfp,
    const int* __restrict__ src, const int* __restrict__ dst,
    const ushort_t* __restrict__ w2hi, const ushort_t* __restrict__ w2lo,
    unsigned* __restrict__ agg, int E) {
    __shared__ char smem[67584];
    char* Whi = smem;
    char* Wlo = smem + 32768;
    int* sdst = (int*)(smem + 65536);
    int* ssrc = sdst + 256;
    float (*R)[64] = (float (*)[64])smem;   // overlays Whi after MFMA phase
    const int t = threadIdx.x;
    const int w = t >> 6, l = t & 63;
    const int e0 = blockIdx.x * 256;
    if (t < 256) { sdst[t] = dst[e0 + t]; ssrc[t] = src[e0 + t]; }
    for (int cid = t; cid < 2048; cid += 512) {
        int c = cid >> 4, ch = cid & 15;
        uint4 vh = *(const uint4*)(w2hi + (size_t)cid * 8);
        uint4 vl = *(const uint4*)(w2lo + (size_t)cid * 8);
        *(uint4*)(Whi + c * 256 + ((ch ^ (c & 15)) << 4)) = vh;
        *(uint4*)(Wlo + c * 256 + ((ch ^ (c & 15)) << 4)) = vl;
    }
    __syncthreads();
    // gather + relu + bf16-split into A-fragments
    bf16x8 ahi[2][4], alo[2][4];
    #pragma unroll
    for (int rt = 0; rt < 2; ++rt) {
        int er = w * 32 + rt * 16 + (l & 15);
        int dn = sdst[er], sn = ssrc[er];
        const float* pa = Afp + (size_t)dn * DH + 8 * (l >> 4);
        const float* pb = Bfp + (size_t)sn * DH + 8 * (l >> 4);
        #pragma unroll
        for (int ks = 0; ks < 4; ++ks) {
            float4 a0 = *(const float4*)(pa + ks * 32);
            float4 a1 = *(const float4*)(pa + ks * 32 + 4);
            float4 b0 = *(const float4*)(pb + ks * 32);
            float4 b1 = *(const float4*)(pb + ks * 32 + 4);
            float v0 = fmaxf(a0.x + b0.x, 0.f), v1 = fmaxf(a0.y + b0.y, 0.f);
            float v2 = fmaxf(a0.z + b0.z, 0.f), v3 = fmaxf(a0.w + b0.w, 0.f);
            float v4 = fmaxf(a1.x + b1.x, 0.f), v5 = fmaxf(a1.y + b1.y, 0.f);
            float v6 = fmaxf(a1.z + b1.z, 0.f), v7 = fmaxf(a1.w + b1.w, 0.f);
            ushort_t h0 = f2bf(v0), h1 = f2bf(v1), h2 = f2bf(v2), h3 = f2bf(v3);
            ushort_t h4 = f2bf(v4), h5 = f2bf(v5), h6 = f2bf(v6), h7 = f2bf(v7);
            bf16x8 hv, lv;
            hv[0] = (short)h0; lv[0] = (short)f2bf(v0 - bf2f(h0));
            hv[1] = (short)h1; lv[1] = (short)f2bf(v1 - bf2f(h1));
            hv[2] = (short)h2; lv[2] = (short)f2bf(v2 - bf2f(h2));
            hv[3] = (short)h3; lv[3] = (short)f2bf(v3 - bf2f(h3));
            hv[4] = (short)h4; lv[4] = (short)f2bf(v4 - bf2f(h4));
            hv[5] = (short)h5; lv[5] = (short)f2bf(v5 - bf2f(h5));
            hv[6] = (short)h6; lv[6] = (short)f2bf(v6 - bf2f(h6));
            hv[7] = (short)h7; lv[7] = (short)f2bf(v7 - bf2f(h7));
            ahi[rt][ks] = hv; alo[rt][ks] = lv;
        }
    }
    f32x4 acc[2][8];
    #pragma unroll
    for (int rt = 0; rt < 2; ++rt)
        #pragma unroll
        for (int ct = 0; ct < 8; ++ct) acc[rt][ct] = (f32x4){0.f, 0.f, 0.f, 0.f};
    #pragma unroll
    for (int ct = 0; ct < 8; ++ct) {
        int colv = ct * 16 + (l & 15);
        #pragma unroll
        for (int ks = 0; ks < 4; ++ks) {
            int chb = ks * 4 + (l >> 4);
            int addr = colv * 256 + ((chb ^ (colv & 15)) << 4);
            bf16x8 bh = *(const bf16x8*)(Whi + addr);
            bf16x8 bl = *(const bf16x8*)(Wlo + addr);
            #pragma unroll
            for (int rt = 0; rt < 2; ++rt) {
                acc[rt][ct] = __builtin_amdgcn_mfma_f32_16x16x32_bf16(ahi[rt][ks], bh, acc[rt][ct], 0, 0, 0);
                acc[rt][ct] = __builtin_amdgcn_mfma_f32_16x16x32_bf16(ahi[rt][ks], bl, acc[rt][ct], 0, 0, 0);
                acc[rt][ct] = __builtin_amdgcn_mfma_f32_16x16x32_bf16(alo[rt][ks], bh, acc[rt][ct], 0, 0, 0);
            }
        }
    }
    // segmented max over sorted dst runs; stage 128 rows x 64 cols at a time in R
    #pragma unroll
    for (int eh = 0; eh < 2; ++eh) {
        #pragma unroll
        for (int chh = 0; chh < 2; ++chh) {
            __syncthreads();
            if ((w >> 2) == eh) {
                #pragma unroll
                for (int rt = 0; rt < 2; ++rt)
                    #pragma unroll
                    for (int c4 = 0; c4 < 4; ++c4) {
                        int ct = chh * 4 + c4;
                        int col64 = c4 * 16 + (l & 15);
                        #pragma unroll
                        for (int i = 0; i < 4; ++i) {
                            int row = (w & 3) * 32 + rt * 16 + (l >> 4) * 4 + i;
                            R[row][col64 ^ (((row >> 2) & 3) << 4)] = acc[rt][ct][i];
                        }
                    }
            }
            __syncthreads();
            int col = t & 63;
            int r0 = (t >> 6) * 16;
            float run = R[r0][col ^ (((r0 >> 2) & 3) << 4)];
            int cur = sdst[eh * 128 + r0];
            #pragma unroll
            for (int rr = r0 + 1; rr < r0 + 16; ++rr) {
                float x = R[rr][col ^ (((rr >> 2) & 3) << 4)];
                int dd = sdst[eh * 128 + rr];
                if (dd != cur) {
                    atomicMax(&agg[(size_t)cur * DH + chh * 64 + col], enc_f(run));
                    cur = dd; run = x;
                } else {
                    run = fmaxf(run, x);
                }
            }
            atomicMax(&agg[(size_t)cur * DH + chh * 64 + col], enc_f(run));
        }
    }
}

// mode 0: h = relu(agg+b2) -> packed (hi|lo) written IN PLACE over agg (same index, same thread)
// mode 1: out = agg+b2 (fp32, no relu)
__global__ void finalize_kernel(unsigned* agg, const float* __restrict__ b2,
                                unsigned* hpk, float* __restrict__ outf, int n, int mode) {
    int i = blockIdx.x * blockDim.x + threadIdx.x;
    int stride = gridDim.x * blockDim.x;
    for (; i < n; i += stride) {
        unsigned uv = agg[i];
        float f = (uv == ENC_NEG_INF) ? 0.0f : dec_f(uv) + b2[i & (DH - 1)];
        if (mode == 0) {
            f = fmaxf(f, 0.0f);
            ushort_t hi = f2bf(f);
            ushort_t lo = f2bf(f - bf2f(hi));
            hpk[i] = (unsigned)hi | ((unsigned)lo << 16);
        } else {
            outf[i] = f;
        }
    }
}

extern "C" void kernel_launch(void* const* d_in, const int* in_sizes, int n_in,
                              void* d_out, int out_size, void* d_ws, size_t ws_size,
                              hipStream_t stream) {
    const float* z  = (const float*)d_in[0];
    const int*   ei = (const int*)d_in[1];
    const float* W1 = (const float*)d_in[2];
    const float* b1 = (const float*)d_in[3];
    const float* W2 = (const float*)d_in[4];
    const float* b2 = (const float*)d_in[5];
    const int N = 50000, D = DH, E = 800000;
    const int* srcp = ei;
    const int* dstp = ei + E;

    // ws: A, B fp32 [N*D]; agg u32 [N*D] (doubles as packed-h buffer);
    //     W tables; cnt/off; sorted src/dst.  ~84 MB total.
    float* Abuf = (float*)d_ws;
    float* Bbuf = Abuf + (size_t)N * D;
    unsigned* agg = (unsigned*)(Bbuf + (size_t)N * D);
    ushort_t* W1t_hi = (ushort_t*)(agg + (size_t)N * D);
    ushort_t* W1t_lo = W1t_hi + NLAYER * 256 * D;
    ushort_t* W2t_hi = W1t_lo + NLAYER * 256 * D;
    ushort_t* W2t_lo = W2t_hi + NLAYER * D * D;
    unsigned* cnt = (unsigned*)(W2t_lo + NLAYER * D * D);
    unsigned* off = cnt + N;
    int* s_src = (int*)(off + N);
    int* s_dst = s_src + E;
    float* outp = (float*)d_out;

    convert_w<<<128, 256, 0, stream>>>(W1, W2, W1t_hi, W1t_lo, W2t_hi, W2t_lo);
    convert_h<<<1024, 256, 0, stream>>>(z, agg, N * D);   // packed h lives in agg buffer

    fill_u<<<256, 256, 0, stream>>>(cnt, N, 0u);
    hist_kernel<<<1024, 256, 0, stream>>>(dstp, cnt, E);
    scan_kernel<<<1, 1024, 0, stream>>>(cnt, off, N);
    scatter_kernel<<<1024, 256, 0, stream>>>(srcp, dstp, off, cnt, s_src, s_dst, E);

    const int nrb = (N + 127) / 128;
    for (int l = 0; l < NLAYER; ++l) {
        // node GEMMs read packed h from agg buffer, then fill_u re-inits agg
        node_gemm<<<nrb, 256, 0, stream>>>(agg, W1t_hi + ((size_t)l * 256) * D,
                                           W1t_lo + ((size_t)l * 256) * D,
                                           b1 + (size_t)l * D, Abuf, N);
        node_gemm<<<nrb, 256, 0, stream>>>(agg, W1t_hi + ((size_t)l * 256 + 128) * D,
                                           W1t_lo + ((size_t)l * 256 + 128) * D,
                                           nullptr, Bbuf, N);
        fill_u<<<2048, 256, 0, stream>>>(agg, N * D, ENC_NEG_INF);
        edge_mlp<<<E / 256, 512, 0, stream>>>(Abuf, Bbuf, s_src, s_dst,
                                              W2t_hi + (size_t)l * D * D,
                                              W2t_lo + (size_t)l * D * D, agg, E);
        finalize_kernel<<<2048, 256, 0, stream>>>(agg, b2 + (size_t)l * D,
                                                  agg, outp, N * D,
                                                  (l < NLAYER - 1) ? 0 : 1);
    }
}